// Round 9
// baseline (123.840 us; speedup 1.0000x reference)
//
#include <hip/hip_runtime.h>

// FANS: B=131072 rows x 16 states, MLP 12->64->64->1 with tanh, fp32 in/out.
// R26: force PACKED f16 math. Evidence: R19/R22/R23/R24 all pinned at ~66us,
// ~50% occ, VALU busy-time 41-42us regardless of structure -> occupancy is
// NOT the lever. Op-count model of the intrinsic math = ~330 VALU/tile
// (~18us); measured ~41us = 2.3x. tanh is 256/330 ops; if clang scalarizes
// the h2 (ext_vector __fp16) arithmetic to per-half v_fma_f16 instead of
// v_pk_fma_f16, the model becomes ~620/tile == the measured gap. That also
// explains structure-independence. AGPR shuttle (+35% max) can't.
// Change (single): tanh_pk rewritten as ONE inline-asm block of VOP3P ops
// (v_pk_max/min/mul/fma_f16) - guaranteed packed encoding, same polynomial.
// Coefficients passed as "v" operands (VOP3P takes no literals). R24's
// no-op "+v" coercions removed (revert to measured R23 body).
// Predict: dispatch 66 -> 50-54us if theory right; dur flat -> pk was
// already emitted -> pivot to inline-asm MFMA (AGPR shuttle). absmax must
// stay 0.0009765625 (same poly/rounding); big shift -> encoding bug, revert.
// Kept: sequential c1-half lifetimes + sched_barrier pins, permlane32_swap
// H-exchange, 32x32x16 MFMA, weights in LDS frag layout, opaque-zero
// anti-LICM, CHUNK=4, split fdot2 accums, launch_bounds(256,4).

#define N_STATES 16
#define CHUNK    4

typedef _Float16 f16x8  __attribute__((ext_vector_type(8)));
typedef float    f32x16 __attribute__((ext_vector_type(16)));
typedef __fp16   h2     __attribute__((ext_vector_type(2)));
typedef unsigned int u32x2 __attribute__((ext_vector_type(2)));

__device__ __forceinline__ h2 pack2(float a, float b) {
    return __builtin_amdgcn_cvt_pkrtz(a, b);
}
__device__ __forceinline__ unsigned int h2_bits(h2 v) {
    union { h2 h; unsigned int u; } x; x.h = v; return x.u;
}
__device__ __forceinline__ h2 bits_h2(unsigned int v) {
    union { unsigned int u; h2 h; } x; x.u = v; return x.h;
}
__device__ __forceinline__ f16x8 u4_to_h8(uint4 v) {
    union { uint4 u; f16x8 h; } x; x.u = v; return x.h;
}
__device__ __forceinline__ uint4 pk8(float4 a, float4 b) {
    return make_uint4(h2_bits(pack2(a.x, a.y)), h2_bits(pack2(a.z, a.w)),
                      h2_bits(pack2(b.x, b.y)), h2_bits(pack2(b.z, b.w)));
}

// Packed-f16 tanh: clamp(+-1.25) then odd Chebyshev poly.
// Inline-asm VOP3P: guaranteed v_pk_* encoding (8 packed ops / 2 values).
__device__ __forceinline__ h2 tanh_pk(h2 x) {
    const h2 hi = {(__fp16)1.25f, (__fp16)1.25f};
    const h2 lo = {(__fp16)-1.25f, (__fp16)-1.25f};
    const h2 k4 = {(__fp16)0.00598591f, (__fp16)0.00598591f};
    const h2 k3 = {(__fp16)-0.03807894f, (__fp16)-0.03807894f};
    const h2 k2 = {(__fp16)0.12576901f, (__fp16)0.12576901f};
    const h2 k1 = {(__fp16)-0.33203310f, (__fp16)-0.33203310f};
    const h2 k0 = {(__fp16)0.99998110f, (__fp16)0.99998110f};
    h2 s, p;
    asm("v_pk_max_f16 %0, %0, %3\n\t"      // x = max(x, lo)
        "v_pk_min_f16 %0, %0, %4\n\t"      // x = min(x, hi)
        "v_pk_mul_f16 %1, %0, %0\n\t"      // s = x*x
        "v_pk_fma_f16 %2, %1, %5, %6\n\t"  // p = s*k4 + k3
        "v_pk_fma_f16 %2, %1, %2, %7\n\t"  // p = s*p + k2
        "v_pk_fma_f16 %2, %1, %2, %8\n\t"  // p = s*p + k1
        "v_pk_fma_f16 %2, %1, %2, %9\n\t"  // p = s*p + k0
        "v_pk_mul_f16 %0, %0, %2"          // x = x*p
        : "+v"(x), "=&v"(s), "=&v"(p)
        : "v"(lo), "v"(hi), "v"(k4), "v"(k3), "v"(k2), "v"(k1), "v"(k0));
    return x;
}

__global__ __launch_bounds__(256, 4) void fans_mfma_kernel(
    const float* __restrict__ x_f, const float* __restrict__ x_b,
    const float* __restrict__ u,   const float* __restrict__ W0,
    const float* __restrict__ W1,  const float* __restrict__ W2,
    float* __restrict__ out)
{
    __shared__ __align__(16) uint4 zplA[256];              // 4 KB: z dwords 0..3
    __shared__ __align__(16) uint2 zplB[256];              // 2 KB: u pair
    __shared__ __align__(16) uint4 sA1[8][64];             // 8 KB: W1 frags [Mh*4+kc][h*32+n]
    __shared__ __align__(16) uint4 sA0[2][64];             // 2 KB: W0 frags [Mh][h*32+n]
    __shared__ __align__(16) unsigned int w2l[32];         // 128 B: W2 pair-packed

    const int s   = blockIdx.y;
    const int tid = threadIdx.x;
    const int b0  = blockIdx.x * (256 * CHUNK);

    const int lid = tid & 63;
    const int w   = tid >> 6;     // wave id; wave w owns local rows [64w,64w+64)
    const int n   = lid & 31;     // batch row within 32-tile / feat row for A
    const int h   = lid >> 5;     // K-half (k = 8h+j)

    // ---- stage weights to LDS in frag layout (once per block) ----
    // sA1[Mh*4+kc][h*32+n] = W1[s][32Mh+n][16kc+8h+0..7] as 8 x f16
    {
        const int r  = tid >> 2;          // 0..63 feature row
        const int kc = tid & 3;           // 0..3 K-chunk
        const float* p = W1 + s * 4096 + r * 64 + kc * 16;
        const float4 v0 = ((const float4*)p)[0];
        const float4 v1 = ((const float4*)p)[1];
        const float4 v2 = ((const float4*)p)[2];
        const float4 v3 = ((const float4*)p)[3];
        sA1[(r >> 5) * 4 + kc][(r & 31)]      = pk8(v0, v1);  // h=0: cols +0..7
        sA1[(r >> 5) * 4 + kc][32 + (r & 31)] = pk8(v2, v3);  // h=1: cols +8..15
    }
    // sA0[Mh][h*32+n] = W0[s][32Mh+n][8h+0..7] (h=1: cols 8..11 + zero pad)
    if (tid < 128) {
        const int r  = tid >> 1;          // 0..63 feature row
        const int hh = tid & 1;
        const float* base = W0 + s * 768 + r * 12;
        uint4 v;
        if (hh == 0) {
            const float4 v0 = *(const float4*)(base + 0);
            const float4 v1 = *(const float4*)(base + 4);
            v = pk8(v0, v1);
        } else {
            const float4 v0 = *(const float4*)(base + 8);   // k=8..11
            v = make_uint4(h2_bits(pack2(v0.x, v0.y)), h2_bits(pack2(v0.z, v0.w)), 0u, 0u);
        }
        sA0[r >> 5][hh * 32 + (r & 31)] = v;
    }
    // w2l[i] = pack2(W2[s][2i], W2[s][2i+1]); layer-3 reads broadcast per h.
    if (tid < 32) {
        const float* w2s = W2 + s * 64;
        w2l[tid] = h2_bits(pack2(w2s[2 * tid], w2s[2 * tid + 1]));
    }
    __syncthreads();

    const int wrap = (s > 8) ? (s - 8) : 0;   // IDX[s] = {0..wrap-1}++{s..15}

    #pragma unroll 1
    for (int ch = 0; ch < CHUNK; ++ch) {
        const int rbase = b0 + ch * 256;

        // ---- phase 1: gather z for own row, pack, write planes ----
        {
            const int row = rbase + tid;
            float zs[8];
            #pragma unroll
            for (int j = 0; j < 8; ++j) {
                const int idx = (j < wrap) ? j : (s + j - wrap);  // uniform
                zs[j] = (idx < 8) ? x_f[row * 8 + idx] : x_b[row * 8 + (idx - 8)];
            }
            const float4 uv = *(const float4*)(u + row * 4);
            zplA[tid] = make_uint4(h2_bits(pack2(zs[0], zs[1])), h2_bits(pack2(zs[2], zs[3])),
                                   h2_bits(pack2(zs[4], zs[5])), h2_bits(pack2(zs[6], zs[7])));
            zplB[tid] = make_uint2(h2_bits(pack2(uv.x, uv.y)), h2_bits(pack2(uv.z, uv.w)));
        }
        // No barrier: wave w reads only rows [64w,64w+64) it wrote itself;
        // weight LDS is read-only after the initial sync.

        // ---- phase 2: two 32-row tiles ----
        #pragma unroll
        for (int m = 0; m < 2; ++m) {
            const int rowb = 64 * w + 32 * m;

            // Opaque zero: defeats LICM/CSE so weight ds_reads stay per-tile
            // (normal HIP loads -> compiler manages lgkmcnt; just un-hoistable).
            unsigned int zero = 0;
            asm("" : "+v"(zero));
            const int lz = lid + (int)zero;

            // z B-frag: B[k=8h+j][n]: h=0 -> z dwords 0..3; h=1 -> u pair + 0
            f16x8 zf;
            if (h == 0) {
                zf = u4_to_h8(zplA[rowb + n]);
            } else {
                const uint2 b = zplB[rowb + n];
                zf = u4_to_h8(make_uint4(b.x, b.y, 0u, 0u));
            }

            const f32x16 z16 = {0.f,0.f,0.f,0.f,0.f,0.f,0.f,0.f,
                                0.f,0.f,0.f,0.f,0.f,0.f,0.f,0.f};
            f32x16 c2a = z16, c2b = z16;

            // ---- per half: c1 -> tanh -> 2 kc MFMAs; c1 regs reused across
            // halves (sched_barrier pins the lifetime).
            #pragma unroll
            for (int half = 0; half < 2; ++half) {
                const f16x8 a0f = u4_to_h8(sA0[half][lz]);
                f32x16 c1 = __builtin_amdgcn_mfma_f32_32x32x16_f16(a0f, zf, z16, 0, 0, 0);
                unsigned int t[8];
                #pragma unroll
                for (int a = 0; a < 4; ++a) {
                    t[2 * a + 0] = h2_bits(tanh_pk(pack2(c1[4 * a],     c1[4 * a + 1])));
                    t[2 * a + 1] = h2_bits(tanh_pk(pack2(c1[4 * a + 2], c1[4 * a + 3])));
                }
                __builtin_amdgcn_sched_barrier(0);
                #pragma unroll
                for (int kk = 0; kk < 2; ++kk) {
                    const int kc = 2 * half + kk;         // 0..3
                    const int q  = 4 * kk;
                    u32x2 r0 = __builtin_amdgcn_permlane32_swap(t[q + 0], t[q + 2], false, false);
                    u32x2 r1 = __builtin_amdgcn_permlane32_swap(t[q + 1], t[q + 3], false, false);
                    const f16x8 hb  = u4_to_h8(make_uint4(r0.x, r1.x, r0.y, r1.y));
                    const f16x8 w1a = u4_to_h8(sA1[kc][lz]);
                    const f16x8 w1b = u4_to_h8(sA1[4 + kc][lz]);
                    c2a = __builtin_amdgcn_mfma_f32_32x32x16_f16(w1a, hb, c2a, 0, 0, 0);
                    c2b = __builtin_amdgcn_mfma_f32_32x32x16_f16(w1b, hb, c2b, 0, 0, 0);
                }
                __builtin_amdgcn_sched_barrier(0);
            }

            // layer 3: packed tanh + v_dot2; W2 pairs broadcast-read from LDS.
            // Split accumulators: 2-deep chains instead of 4-deep.
            const unsigned int* w2z = &w2l[zero];
            float p0 = 0.f, p1 = 0.f, q0 = 0.f, q1 = 0.f;
            #pragma unroll
            for (int a = 0; a < 4; ++a) {
                const int r = 4 * a;
                const uint2 wa = *(const uint2*)&w2z[4 * a + 2 * h];        // Mh=0
                const uint2 wb = *(const uint2*)&w2z[16 + 4 * a + 2 * h];   // Mh=1
                if (a & 1) {
                    p1 = __builtin_amdgcn_fdot2(tanh_pk(pack2(c2a[r], c2a[r + 1])), bits_h2(wa.x), p1, false);
                    p1 = __builtin_amdgcn_fdot2(tanh_pk(pack2(c2a[r + 2], c2a[r + 3])), bits_h2(wa.y), p1, false);
                    q1 = __builtin_amdgcn_fdot2(tanh_pk(pack2(c2b[r], c2b[r + 1])), bits_h2(wb.x), q1, false);
                    q1 = __builtin_amdgcn_fdot2(tanh_pk(pack2(c2b[r + 2], c2b[r + 3])), bits_h2(wb.y), q1, false);
                } else {
                    p0 = __builtin_amdgcn_fdot2(tanh_pk(pack2(c2a[r], c2a[r + 1])), bits_h2(wa.x), p0, false);
                    p0 = __builtin_amdgcn_fdot2(tanh_pk(pack2(c2a[r + 2], c2a[r + 3])), bits_h2(wa.y), p0, false);
                    q0 = __builtin_amdgcn_fdot2(tanh_pk(pack2(c2b[r], c2b[r + 1])), bits_h2(wb.x), q0, false);
                    q0 = __builtin_amdgcn_fdot2(tanh_pk(pack2(c2b[r + 2], c2b[r + 3])), bits_h2(wb.y), q0, false);
                }
            }
            float acc = (p0 + p1) + (q0 + q1);
            acc += __shfl_xor(acc, 32);       // combine h=0/h=1 halves

            if (lid < 32)
                out[(rbase + rowb + n) * N_STATES + s] = acc;
        }
    }
}

extern "C" void kernel_launch(void* const* d_in, const int* in_sizes, int n_in,
                              void* d_out, int out_size, void* d_ws, size_t ws_size,
                              hipStream_t stream) {
    const float* x_f = (const float*)d_in[0];
    const float* x_b = (const float*)d_in[1];
    const float* u   = (const float*)d_in[2];
    const float* W0  = (const float*)d_in[3];
    const float* W1  = (const float*)d_in[4];
    const float* W2  = (const float*)d_in[5];
    float* out = (float*)d_out;

    const int nb = in_sizes[0] / 8;                 // 131072 = 128 * 1024
    dim3 grid(nb / (256 * CHUNK), N_STATES);        // (128, 16) = 2048 blocks
    fans_mfma_kernel<<<grid, 256, 0, stream>>>(x_f, x_b, u, W0, W1, W2, out);
}

// Round 10
// 121.351 us; speedup vs baseline: 1.0205x; 1.0205x over previous
//
#include <hip/hip_runtime.h>

// FANS: B=131072 rows x 16 states, MLP 12->64->64->1 with tanh, fp32 in/out.
// R27: fill the stall bubbles. R18-R26 established: dur pinned 65-66us,
// VALUBusy ~64%, occ ~50% across ALL regalloc/structure/encoding changes ->
// the lever is idle-VALU, not op selection or occupancy.
// Two un-attacked stall sources:
// (1) Phase-1 gather bubble: 8 stride-32B scalar loads (~200-300cy, L3-hit)
//     feed the zpl pack immediately; all 4 waves hit it at the same chunk
//     boundary -> SIMD idles. Fix = T14 issue-early: prefetch chunk ch+1's
//     zs/uv into regs BEFORE the 2-tile compute of chunk ch; vmcnt wait
//     lands after ~2000cy of MFMA/tanh. +12 VGPR (52 arch, fits (256,4)).
// (2) sched_barrier(0) pins: perf-neutral for their original goal (R22==R20)
//     and m141 says order-pinning blocks MFMA-shadow filling. Removed.
// Predict: VALUBusy 64->71-76%, dispatch 65.5->57-60us, VGPR->~52, absmax
// identical. Falsifier: dur flat -> bubble theory dead; next round is a
// DCE-guarded identity-tanh ablation to split the VALU budget empirically.
// Kept: asm-VOP3P tanh (R26), permlane32_swap H-exchange, 32x32x16 MFMA,
// weights in LDS frag layout, opaque-zero anti-LICM, CHUNK=4, split fdot2,
// launch_bounds(256,4).

#define N_STATES 16
#define CHUNK    4

typedef _Float16 f16x8  __attribute__((ext_vector_type(8)));
typedef float    f32x16 __attribute__((ext_vector_type(16)));
typedef __fp16   h2     __attribute__((ext_vector_type(2)));
typedef unsigned int u32x2 __attribute__((ext_vector_type(2)));

__device__ __forceinline__ h2 pack2(float a, float b) {
    return __builtin_amdgcn_cvt_pkrtz(a, b);
}
__device__ __forceinline__ unsigned int h2_bits(h2 v) {
    union { h2 h; unsigned int u; } x; x.h = v; return x.u;
}
__device__ __forceinline__ h2 bits_h2(unsigned int v) {
    union { unsigned int u; h2 h; } x; x.u = v; return x.h;
}
__device__ __forceinline__ f16x8 u4_to_h8(uint4 v) {
    union { uint4 u; f16x8 h; } x; x.u = v; return x.h;
}
__device__ __forceinline__ uint4 pk8(float4 a, float4 b) {
    return make_uint4(h2_bits(pack2(a.x, a.y)), h2_bits(pack2(a.z, a.w)),
                      h2_bits(pack2(b.x, b.y)), h2_bits(pack2(b.z, b.w)));
}

// Packed-f16 tanh: clamp(+-1.25) then odd Chebyshev poly.
// Inline-asm VOP3P: guaranteed v_pk_* encoding (8 packed ops / 2 values).
__device__ __forceinline__ h2 tanh_pk(h2 x) {
    const h2 hi = {(__fp16)1.25f, (__fp16)1.25f};
    const h2 lo = {(__fp16)-1.25f, (__fp16)-1.25f};
    const h2 k4 = {(__fp16)0.00598591f, (__fp16)0.00598591f};
    const h2 k3 = {(__fp16)-0.03807894f, (__fp16)-0.03807894f};
    const h2 k2 = {(__fp16)0.12576901f, (__fp16)0.12576901f};
    const h2 k1 = {(__fp16)-0.33203310f, (__fp16)-0.33203310f};
    const h2 k0 = {(__fp16)0.99998110f, (__fp16)0.99998110f};
    h2 s, p;
    asm("v_pk_max_f16 %0, %0, %3\n\t"      // x = max(x, lo)
        "v_pk_min_f16 %0, %0, %4\n\t"      // x = min(x, hi)
        "v_pk_mul_f16 %1, %0, %0\n\t"      // s = x*x
        "v_pk_fma_f16 %2, %1, %5, %6\n\t"  // p = s*k4 + k3
        "v_pk_fma_f16 %2, %1, %2, %7\n\t"  // p = s*p + k2
        "v_pk_fma_f16 %2, %1, %2, %8\n\t"  // p = s*p + k1
        "v_pk_fma_f16 %2, %1, %2, %9\n\t"  // p = s*p + k0
        "v_pk_mul_f16 %0, %0, %2"          // x = x*p
        : "+v"(x), "=&v"(s), "=&v"(p)
        : "v"(lo), "v"(hi), "v"(k4), "v"(k3), "v"(k2), "v"(k1), "v"(k0));
    return x;
}

__global__ __launch_bounds__(256, 4) void fans_mfma_kernel(
    const float* __restrict__ x_f, const float* __restrict__ x_b,
    const float* __restrict__ u,   const float* __restrict__ W0,
    const float* __restrict__ W1,  const float* __restrict__ W2,
    float* __restrict__ out)
{
    __shared__ __align__(16) uint4 zplA[256];              // 4 KB: z dwords 0..3
    __shared__ __align__(16) uint2 zplB[256];              // 2 KB: u pair
    __shared__ __align__(16) uint4 sA1[8][64];             // 8 KB: W1 frags [Mh*4+kc][h*32+n]
    __shared__ __align__(16) uint4 sA0[2][64];             // 2 KB: W0 frags [Mh][h*32+n]
    __shared__ __align__(16) unsigned int w2l[32];         // 128 B: W2 pair-packed

    const int s   = blockIdx.y;
    const int tid = threadIdx.x;
    const int b0  = blockIdx.x * (256 * CHUNK);

    const int lid = tid & 63;
    const int w   = tid >> 6;     // wave id; wave w owns local rows [64w,64w+64)
    const int n   = lid & 31;     // batch row within 32-tile / feat row for A
    const int h   = lid >> 5;     // K-half (k = 8h+j)

    // ---- stage weights to LDS in frag layout (once per block) ----
    // sA1[Mh*4+kc][h*32+n] = W1[s][32Mh+n][16kc+8h+0..7] as 8 x f16
    {
        const int r  = tid >> 2;          // 0..63 feature row
        const int kc = tid & 3;           // 0..3 K-chunk
        const float* p = W1 + s * 4096 + r * 64 + kc * 16;
        const float4 v0 = ((const float4*)p)[0];
        const float4 v1 = ((const float4*)p)[1];
        const float4 v2 = ((const float4*)p)[2];
        const float4 v3 = ((const float4*)p)[3];
        sA1[(r >> 5) * 4 + kc][(r & 31)]      = pk8(v0, v1);  // h=0: cols +0..7
        sA1[(r >> 5) * 4 + kc][32 + (r & 31)] = pk8(v2, v3);  // h=1: cols +8..15
    }
    // sA0[Mh][h*32+n] = W0[s][32Mh+n][8h+0..7] (h=1: cols 8..11 + zero pad)
    if (tid < 128) {
        const int r  = tid >> 1;          // 0..63 feature row
        const int hh = tid & 1;
        const float* base = W0 + s * 768 + r * 12;
        uint4 v;
        if (hh == 0) {
            const float4 v0 = *(const float4*)(base + 0);
            const float4 v1 = *(const float4*)(base + 4);
            v = pk8(v0, v1);
        } else {
            const float4 v0 = *(const float4*)(base + 8);   // k=8..11
            v = make_uint4(h2_bits(pack2(v0.x, v0.y)), h2_bits(pack2(v0.z, v0.w)), 0u, 0u);
        }
        sA0[r >> 5][hh * 32 + (r & 31)] = v;
    }
    // w2l[i] = pack2(W2[s][2i], W2[s][2i+1]); layer-3 reads broadcast per h.
    if (tid < 32) {
        const float* w2s = W2 + s * 64;
        w2l[tid] = h2_bits(pack2(w2s[2 * tid], w2s[2 * tid + 1]));
    }
    __syncthreads();

    const int wrap = (s > 8) ? (s - 8) : 0;   // IDX[s] = {0..wrap-1}++{s..15}

    // ---- z prefetch registers: chunk 0 loaded ahead of the loop ----
    float zs[8]; float4 uv;
    {
        const int row = b0 + tid;
        #pragma unroll
        for (int j = 0; j < 8; ++j) {
            const int idx = (j < wrap) ? j : (s + j - wrap);  // uniform
            zs[j] = (idx < 8) ? x_f[row * 8 + idx] : x_b[row * 8 + (idx - 8)];
        }
        uv = *(const float4*)(u + row * 4);
    }

    #pragma unroll 1
    for (int ch = 0; ch < CHUNK; ++ch) {
        const int rbase = b0 + ch * 256;

        // ---- phase 1: pack prefetched z, write planes ----
        zplA[tid] = make_uint4(h2_bits(pack2(zs[0], zs[1])), h2_bits(pack2(zs[2], zs[3])),
                               h2_bits(pack2(zs[4], zs[5])), h2_bits(pack2(zs[6], zs[7])));
        zplB[tid] = make_uint2(h2_bits(pack2(uv.x, uv.y)), h2_bits(pack2(uv.z, uv.w)));
        // No barrier: wave w reads only rows [64w,64w+64) it wrote itself;
        // weight LDS is read-only after the initial sync.

        // ---- issue next chunk's gather NOW (T14 issue-early): the vmcnt
        // wait lands at next iteration's pack, hidden under the 2-tile
        // compute (~2000cy) below.
        if (ch + 1 < CHUNK) {
            const int row = rbase + 256 + tid;
            #pragma unroll
            for (int j = 0; j < 8; ++j) {
                const int idx = (j < wrap) ? j : (s + j - wrap);  // uniform
                zs[j] = (idx < 8) ? x_f[row * 8 + idx] : x_b[row * 8 + (idx - 8)];
            }
            uv = *(const float4*)(u + row * 4);
        }

        // ---- phase 2: two 32-row tiles ----
        #pragma unroll
        for (int m = 0; m < 2; ++m) {
            const int rowb = 64 * w + 32 * m;

            // Opaque zero: defeats LICM/CSE so weight ds_reads stay per-tile
            // (normal HIP loads -> compiler manages lgkmcnt; just un-hoistable).
            unsigned int zero = 0;
            asm("" : "+v"(zero));
            const int lz = lid + (int)zero;

            // z B-frag: B[k=8h+j][n]: h=0 -> z dwords 0..3; h=1 -> u pair + 0
            f16x8 zf;
            if (h == 0) {
                zf = u4_to_h8(zplA[rowb + n]);
            } else {
                const uint2 b = zplB[rowb + n];
                zf = u4_to_h8(make_uint4(b.x, b.y, 0u, 0u));
            }

            const f32x16 z16 = {0.f,0.f,0.f,0.f,0.f,0.f,0.f,0.f,
                                0.f,0.f,0.f,0.f,0.f,0.f,0.f,0.f};
            f32x16 c2a = z16, c2b = z16;

            // ---- per half: c1 -> tanh -> 2 kc MFMAs (no sched pins: let the
            // scheduler fill MFMA shadows with the other half's work).
            #pragma unroll
            for (int half = 0; half < 2; ++half) {
                const f16x8 a0f = u4_to_h8(sA0[half][lz]);
                f32x16 c1 = __builtin_amdgcn_mfma_f32_32x32x16_f16(a0f, zf, z16, 0, 0, 0);
                unsigned int t[8];
                #pragma unroll
                for (int a = 0; a < 4; ++a) {
                    t[2 * a + 0] = h2_bits(tanh_pk(pack2(c1[4 * a],     c1[4 * a + 1])));
                    t[2 * a + 1] = h2_bits(tanh_pk(pack2(c1[4 * a + 2], c1[4 * a + 3])));
                }
                #pragma unroll
                for (int kk = 0; kk < 2; ++kk) {
                    const int kc = 2 * half + kk;         // 0..3
                    const int q  = 4 * kk;
                    u32x2 r0 = __builtin_amdgcn_permlane32_swap(t[q + 0], t[q + 2], false, false);
                    u32x2 r1 = __builtin_amdgcn_permlane32_swap(t[q + 1], t[q + 3], false, false);
                    const f16x8 hb  = u4_to_h8(make_uint4(r0.x, r1.x, r0.y, r1.y));
                    const f16x8 w1a = u4_to_h8(sA1[kc][lz]);
                    const f16x8 w1b = u4_to_h8(sA1[4 + kc][lz]);
                    c2a = __builtin_amdgcn_mfma_f32_32x32x16_f16(w1a, hb, c2a, 0, 0, 0);
                    c2b = __builtin_amdgcn_mfma_f32_32x32x16_f16(w1b, hb, c2b, 0, 0, 0);
                }
            }

            // layer 3: packed tanh + v_dot2; W2 pairs broadcast-read from LDS.
            // Split accumulators: 2-deep chains instead of 4-deep.
            const unsigned int* w2z = &w2l[zero];
            float p0 = 0.f, p1 = 0.f, q0 = 0.f, q1 = 0.f;
            #pragma unroll
            for (int a = 0; a < 4; ++a) {
                const int r = 4 * a;
                const uint2 wa = *(const uint2*)&w2z[4 * a + 2 * h];        // Mh=0
                const uint2 wb = *(const uint2*)&w2z[16 + 4 * a + 2 * h];   // Mh=1
                if (a & 1) {
                    p1 = __builtin_amdgcn_fdot2(tanh_pk(pack2(c2a[r], c2a[r + 1])), bits_h2(wa.x), p1, false);
                    p1 = __builtin_amdgcn_fdot2(tanh_pk(pack2(c2a[r + 2], c2a[r + 3])), bits_h2(wa.y), p1, false);
                    q1 = __builtin_amdgcn_fdot2(tanh_pk(pack2(c2b[r], c2b[r + 1])), bits_h2(wb.x), q1, false);
                    q1 = __builtin_amdgcn_fdot2(tanh_pk(pack2(c2b[r + 2], c2b[r + 3])), bits_h2(wb.y), q1, false);
                } else {
                    p0 = __builtin_amdgcn_fdot2(tanh_pk(pack2(c2a[r], c2a[r + 1])), bits_h2(wa.x), p0, false);
                    p0 = __builtin_amdgcn_fdot2(tanh_pk(pack2(c2a[r + 2], c2a[r + 3])), bits_h2(wa.y), p0, false);
                    q0 = __builtin_amdgcn_fdot2(tanh_pk(pack2(c2b[r], c2b[r + 1])), bits_h2(wb.x), q0, false);
                    q0 = __builtin_amdgcn_fdot2(tanh_pk(pack2(c2b[r + 2], c2b[r + 3])), bits_h2(wb.y), q0, false);
                }
            }
            float acc = (p0 + p1) + (q0 + q1);
            acc += __shfl_xor(acc, 32);       // combine h=0/h=1 halves

            if (lid < 32)
                out[(rbase + rowb + n) * N_STATES + s] = acc;
        }
    }
}

extern "C" void kernel_launch(void* const* d_in, const int* in_sizes, int n_in,
                              void* d_out, int out_size, void* d_ws, size_t ws_size,
                              hipStream_t stream) {
    const float* x_f = (const float*)d_in[0];
    const float* x_b = (const float*)d_in[1];
    const float* u   = (const float*)d_in[2];
    const float* W0  = (const float*)d_in[3];
    const float* W1  = (const float*)d_in[4];
    const float* W2  = (const float*)d_in[5];
    float* out = (float*)d_out;

    const int nb = in_sizes[0] / 8;                 // 131072 = 128 * 1024
    dim3 grid(nb / (256 * CHUNK), N_STATES);        // (128, 16) = 2048 blocks
    fans_mfma_kernel<<<grid, 256, 0, stream>>>(x_f, x_b, u, W0, W1, W2, out);
}